// Round 2
// baseline (629.661 us; speedup 1.0000x reference)
//
#include <hip/hip_runtime.h>

// Problem constants (B,N,F_in,F_out fixed by setup_inputs)
#define NB   4
#define NN   2048
#define FIN  512
#define FOUT 512
#define NHD  8
#define DH   64
#define VC   576   // padded V columns: 512 data (8 heads x 64) + 8 Z cols + 56 zero pad
#define SLOPE 0.2f

// ---------------------------------------------------------------------------
// K1: Whr[b][h][j][d] = leaky_relu( (h @ W_r)[row][col] ) with raw-reshape remap
//     row = b*2048+n ; h = n>>8 ; j = (n&255)*8 + (col>>6) ; d = col&63
// ---------------------------------------------------------------------------
__global__ __launch_bounds__(256) void k_gemm_whr(
    const float* __restrict__ hin,   // f32 [NB*NN][FIN]
    const float* __restrict__ Wr,    // f32 [FIN][FOUT]
    float* __restrict__ Whr)         // f32 [NB][NHD][NN][DH]
{
  __shared__ float sA[32][65];  // [k][m]
  __shared__ float sB[32][65];  // [k][n]
  const int row0 = blockIdx.y << 6;
  const int col0 = blockIdx.x << 6;
  const int tid  = threadIdx.x;
  const int tx = tid & 15, ty = tid >> 4;
  const int ar = tid >> 2, ak = (tid & 3) << 3;   // A tile: 64 rows x 32 k
  const int bk = tid >> 3, bc = (tid & 7) << 3;   // B tile: 32 k x 64 cols
  float acc[4][4] = {{0.f}};
  const float* pA = hin + (size_t)(row0 + ar) * FIN + ak;
  const float* pB = Wr + (size_t)bk * FOUT + col0 + bc;

  for (int k0 = 0; k0 < FIN; k0 += 32) {
    float4 ua0 = *(const float4*)(pA + k0);
    float4 ua1 = *(const float4*)(pA + k0 + 4);
    float4 ub0 = *(const float4*)(pB + (size_t)k0 * FOUT);
    float4 ub1 = *(const float4*)(pB + (size_t)k0 * FOUT + 4);
    sA[ak+0][ar] = ua0.x; sA[ak+1][ar] = ua0.y;
    sA[ak+2][ar] = ua0.z; sA[ak+3][ar] = ua0.w;
    sA[ak+4][ar] = ua1.x; sA[ak+5][ar] = ua1.y;
    sA[ak+6][ar] = ua1.z; sA[ak+7][ar] = ua1.w;
    sB[bk][bc+0] = ub0.x; sB[bk][bc+1] = ub0.y;
    sB[bk][bc+2] = ub0.z; sB[bk][bc+3] = ub0.w;
    sB[bk][bc+4] = ub1.x; sB[bk][bc+5] = ub1.y;
    sB[bk][bc+6] = ub1.z; sB[bk][bc+7] = ub1.w;
    __syncthreads();
#pragma unroll
    for (int kk = 0; kk < 32; ++kk) {
      float a0 = sA[kk][ty*4+0], a1 = sA[kk][ty*4+1];
      float a2 = sA[kk][ty*4+2], a3 = sA[kk][ty*4+3];
      float b0 = sB[kk][tx*4+0], b1 = sB[kk][tx*4+1];
      float b2 = sB[kk][tx*4+2], b3 = sB[kk][tx*4+3];
      acc[0][0] += a0*b0; acc[0][1] += a0*b1; acc[0][2] += a0*b2; acc[0][3] += a0*b3;
      acc[1][0] += a1*b0; acc[1][1] += a1*b1; acc[1][2] += a1*b2; acc[1][3] += a1*b3;
      acc[2][0] += a2*b0; acc[2][1] += a2*b1; acc[2][2] += a2*b2; acc[2][3] += a2*b3;
      acc[3][0] += a3*b0; acc[3][1] += a3*b1; acc[3][2] += a3*b2; acc[3][3] += a3*b3;
    }
    __syncthreads();
  }

  // epilogue: leaky_relu + remapped store (dest contiguous in d -> float4)
  const int colb = col0 + tx*4;
#pragma unroll
  for (int i = 0; i < 4; ++i) {
    int grow = row0 + ty*4 + i;
    int b = grow >> 11;
    int n = grow & 2047;
    int hh = n >> 8;
    int jj = ((n & 255) << 3) | (colb >> 6);   // colb>>6 constant across the 4 cols
    int dd = colb & 63;
    float4 v;
    v.x = acc[i][0] > 0.f ? acc[i][0] : SLOPE*acc[i][0];
    v.y = acc[i][1] > 0.f ? acc[i][1] : SLOPE*acc[i][1];
    v.z = acc[i][2] > 0.f ? acc[i][2] : SLOPE*acc[i][2];
    v.w = acc[i][3] > 0.f ? acc[i][3] : SLOPE*acc[i][3];
    *(float4*)(Whr + (((size_t)(b*NHD + hh) * NN) + jj) * DH + dd) = v;
  }
}

// ---------------------------------------------------------------------------
// K2: er[row] = dot(Whr[row][0..63], a)   (row = (b*8+h)*2048 + j), 1 wave/row
// ---------------------------------------------------------------------------
__global__ __launch_bounds__(256) void k_er(
    const float* __restrict__ Whr, const float* __restrict__ av,
    float* __restrict__ er)
{
  int gtid = blockIdx.x * 256 + threadIdx.x;
  int row  = gtid >> 6;
  int lane = threadIdx.x & 63;
  float v = Whr[(size_t)row * DH + lane] * av[lane];
#pragma unroll
  for (int off = 32; off; off >>= 1) v += __shfl_down(v, off, 64);
  if (lane == 0) er[row] = v;
}

// ---------------------------------------------------------------------------
// K3: per (b,h): w[j] = exp(er[j] - max_j er)   (in place), 1 block per (b,h)
// ---------------------------------------------------------------------------
__global__ __launch_bounds__(256) void k_softmax_w(float* __restrict__ er)
{
  __shared__ float wm[4];
  float* p = er + (size_t)blockIdx.x * NN;
  float m = -1e30f;
  for (int j = threadIdx.x; j < NN; j += 256) m = fmaxf(m, p[j]);
#pragma unroll
  for (int off = 32; off; off >>= 1) m = fmaxf(m, __shfl_down(m, off, 64));
  if ((threadIdx.x & 63) == 0) wm[threadIdx.x >> 6] = m;
  __syncthreads();
  float mm = fmaxf(fmaxf(wm[0], wm[1]), fmaxf(wm[2], wm[3]));
  for (int j = threadIdx.x; j < NN; j += 256) p[j] = expf(p[j] - mm);
}

// ---------------------------------------------------------------------------
// K4: V[b][j][c]: c<512 -> w[b,h,j]*Whr[b,h,j,d] (h=c>>6,d=c&63);
//                 512<=c<520 -> w[b,c-512,j];  else 0 (pad)
// ---------------------------------------------------------------------------
__global__ __launch_bounds__(256) void k_build_v(
    const float* __restrict__ Whr, const float* __restrict__ w,
    float* __restrict__ V)
{
  int idx = blockIdx.x * 256 + threadIdx.x;   // over NB*NN*VC
  int c  = idx % VC;
  int bj = idx / VC;
  int b = bj >> 11, j = bj & 2047;
  float v = 0.f;
  if (c < 512) {
    int hh = c >> 6, dd = c & 63;
    int r = (b*NHD + hh)*NN + j;
    v = w[r] * Whr[(size_t)r * DH + dd];
  } else if (c < 520) {
    v = w[(b*NHD + (c - 512))*NN + j];
  }
  V[idx] = v;
}

// ---------------------------------------------------------------------------
// K5: C[b] = A[b] @ V[b]   (A = adj>0 as 0/1 float, 2048x2048; V 2048xVC)
// ---------------------------------------------------------------------------
__global__ __launch_bounds__(256) void k_attn_mm(
    const int* __restrict__ adj, const float* __restrict__ V,
    float* __restrict__ C)
{
  __shared__ float sA[32][65];  // [j][i]
  __shared__ float sV[32][65];  // [j][c]
  const int b  = blockIdx.z;
  const int i0 = blockIdx.y << 6;
  const int c0 = blockIdx.x << 6;
  const int tid = threadIdx.x;
  const int tx = tid & 15, ty = tid >> 4;
  const int ar = tid >> 2, ak = (tid & 3) << 3;  // adj tile: 64 i x 32 j
  const int vk = tid >> 3, vc = (tid & 7) << 3;  // V tile:   32 j x 64 c
  float acc[4][4] = {{0.f}};
  const int*   adjp = adj + (size_t)b * NN * NN + (size_t)(i0 + ar) * NN + ak;
  const float* Vp   = V   + (size_t)b * NN * VC + (size_t)vk * VC + c0 + vc;

  for (int j0 = 0; j0 < NN; j0 += 32) {
    int4 q0 = *(const int4*)(adjp + j0);
    int4 q1 = *(const int4*)(adjp + j0 + 4);
    sA[ak+0][ar] = q0.x > 0 ? 1.f : 0.f;
    sA[ak+1][ar] = q0.y > 0 ? 1.f : 0.f;
    sA[ak+2][ar] = q0.z > 0 ? 1.f : 0.f;
    sA[ak+3][ar] = q0.w > 0 ? 1.f : 0.f;
    sA[ak+4][ar] = q1.x > 0 ? 1.f : 0.f;
    sA[ak+5][ar] = q1.y > 0 ? 1.f : 0.f;
    sA[ak+6][ar] = q1.z > 0 ? 1.f : 0.f;
    sA[ak+7][ar] = q1.w > 0 ? 1.f : 0.f;
    float4 f0 = *(const float4*)(Vp + (size_t)j0 * VC);
    float4 f1 = *(const float4*)(Vp + (size_t)j0 * VC + 4);
    sV[vk][vc+0] = f0.x; sV[vk][vc+1] = f0.y; sV[vk][vc+2] = f0.z; sV[vk][vc+3] = f0.w;
    sV[vk][vc+4] = f1.x; sV[vk][vc+5] = f1.y; sV[vk][vc+6] = f1.z; sV[vk][vc+7] = f1.w;
    __syncthreads();
#pragma unroll
    for (int kk = 0; kk < 32; ++kk) {
      float a0 = sA[kk][ty*4+0], a1 = sA[kk][ty*4+1];
      float a2 = sA[kk][ty*4+2], a3 = sA[kk][ty*4+3];
      float b0 = sV[kk][tx*4+0], b1 = sV[kk][tx*4+1];
      float b2 = sV[kk][tx*4+2], b3 = sV[kk][tx*4+3];
      acc[0][0] += a0*b0; acc[0][1] += a0*b1; acc[0][2] += a0*b2; acc[0][3] += a0*b3;
      acc[1][0] += a1*b0; acc[1][1] += a1*b1; acc[1][2] += a1*b2; acc[1][3] += a1*b3;
      acc[2][0] += a2*b0; acc[2][1] += a2*b1; acc[2][2] += a2*b2; acc[2][3] += a2*b3;
      acc[3][0] += a3*b0; acc[3][1] += a3*b1; acc[3][2] += a3*b2; acc[3][3] += a3*b3;
    }
    __syncthreads();
  }
#pragma unroll
  for (int i = 0; i < 4; ++i) {
    float4 v; v.x = acc[i][0]; v.y = acc[i][1]; v.z = acc[i][2]; v.w = acc[i][3];
    *(float4*)(C + ((size_t)b*NN + i0 + ty*4 + i) * VC + c0 + tx*4) = v;
  }
}

// ---------------------------------------------------------------------------
// K6: out[b][n][f] = elu( C[b][i][h*64+d] / C[b][i][512+h] )
//     n = h*256 + (i>>3), f = (i&7)*64 + d
// ---------------------------------------------------------------------------
__global__ __launch_bounds__(256) void k_epilogue(
    const float* __restrict__ C, float* __restrict__ out)
{
  int idx = blockIdx.x * 256 + threadIdx.x;  // ((b*NN+i)*8+h)*64+d
  int d  = idx & 63;
  int t  = idx >> 6;
  int hh = t & 7;
  int bi = t >> 3;           // b*NN + i
  int i  = bi & 2047, b = bi >> 11;
  float num = C[(size_t)bi * VC + (hh << 6) + d];
  float den = C[(size_t)bi * VC + 512 + hh];
  float v = num / den;
  v = v > 0.f ? v : expm1f(v);
  int n = (hh << 8) | (i >> 3);
  int f = ((i & 7) << 6) | d;
  out[((size_t)b * NN + n) * FOUT + f] = v;
}

// ---------------------------------------------------------------------------
extern "C" void kernel_launch(void* const* d_in, const int* in_sizes, int n_in,
                              void* d_out, int out_size, void* d_ws, size_t ws_size,
                              hipStream_t stream)
{
  const float* hin = (const float*)d_in[0];   // h   f32 [4,2048,512]
  const int*   adj = (const int*)d_in[1];     // adj int32 [4,2048,2048]
  // d_in[2] = W_l : mathematically dead (softmax(el[i]+er[j]) == softmax(er[j]))
  const float* Wr  = (const float*)d_in[3];   // W_r f32 [512,512]
  const float* av  = (const float*)d_in[4];   // a   f32 [64,1]
  float* out = (float*)d_out;

  char* ws = (char*)d_ws;
  const size_t vBytes = (size_t)NB * NN * VC * 4;   // 18,874,368 B
  float* V    = (float*)ws;                         // [0, vBytes)
  float* Whr  = (float*)(ws + vBytes);              // 16.78 MB, dead after K4
  float* C    = Whr;                                // reuse Whr region (needs vBytes)
  float* wexp = (float*)(ws + 2 * vBytes);          // er then w in place, 256 KB
  // total ws use: 2*vBytes + 262144 = ~38.0 MB

  k_gemm_whr<<<dim3(FOUT/64, NB*NN/64), 256, 0, stream>>>(hin, Wr, Whr);
  k_er      <<<dim3(NB*NHD*NN/4), 256, 0, stream>>>(Whr, av, wexp);
  k_softmax_w<<<dim3(NB*NHD), 256, 0, stream>>>(wexp);
  k_build_v <<<dim3(NB*NN*VC/256), 256, 0, stream>>>(Whr, wexp, V);
  k_attn_mm <<<dim3(VC/64, NN/64, NB), 256, 0, stream>>>(adj, V, C);
  k_epilogue<<<dim3(NB*NN*FOUT/256), 256, 0, stream>>>(C, out);
}

// Round 3
// 284.787 us; speedup vs baseline: 2.2110x; 2.2110x over previous
//
#include <hip/hip_runtime.h>

// Problem constants (B,N,F_in,F_out fixed by setup_inputs)
#define NB   4
#define NN   2048
#define FIN  512
#define FOUT 512
#define NHD  8
#define DH   64
#define VC   576   // padded V columns: 512 data (8 heads x 64) + 8 Z cols + 56 zero pad
#define SLOPE 0.2f

typedef __attribute__((ext_vector_type(8)))  short bhalf8;
typedef __attribute__((ext_vector_type(16))) float f32x16;

__device__ __forceinline__ void load_lds16(const void* g, void* l) {
  __builtin_amdgcn_global_load_lds(
      (const __attribute__((address_space(1))) unsigned int*)g,
      (__attribute__((address_space(3))) unsigned int*)l, 16, 0, 0);
}

// RNE float->bf16 pair pack (values finite, no NaN in this pipeline)
__device__ __forceinline__ unsigned int bfpair(float lo, float hi) {
  unsigned int a = __float_as_uint(lo), b = __float_as_uint(hi);
  a = (a + 0x7FFFu + ((a >> 16) & 1u)) >> 16;
  b = (b + 0x7FFFu + ((b >> 16) & 1u)) & 0xFFFF0000u;
  return a | b;
}

// ---------------------------------------------------------------------------
// K1: Whr[b][h][j][d] = leaky_relu( (h @ W_r)[row][col] ) with raw-reshape remap
//     row = b*2048+n ; h = n>>8 ; j = (n&255)*8 + (col>>6) ; d = col&63
// ---------------------------------------------------------------------------
__global__ __launch_bounds__(256) void k_gemm_whr(
    const float* __restrict__ hin,   // f32 [NB*NN][FIN]
    const float* __restrict__ Wr,    // f32 [FIN][FOUT]
    float* __restrict__ Whr)         // f32 [NB][NHD][NN][DH]
{
  __shared__ float sA[32][65];  // [k][m]
  __shared__ float sB[32][65];  // [k][n]
  const int row0 = blockIdx.y << 6;
  const int col0 = blockIdx.x << 6;
  const int tid  = threadIdx.x;
  const int tx = tid & 15, ty = tid >> 4;
  const int ar = tid >> 2, ak = (tid & 3) << 3;   // A tile: 64 rows x 32 k
  const int bk = tid >> 3, bc = (tid & 7) << 3;   // B tile: 32 k x 64 cols
  float acc[4][4] = {{0.f}};
  const float* pA = hin + (size_t)(row0 + ar) * FIN + ak;
  const float* pB = Wr + (size_t)bk * FOUT + col0 + bc;

  for (int k0 = 0; k0 < FIN; k0 += 32) {
    float4 ua0 = *(const float4*)(pA + k0);
    float4 ua1 = *(const float4*)(pA + k0 + 4);
    float4 ub0 = *(const float4*)(pB + (size_t)k0 * FOUT);
    float4 ub1 = *(const float4*)(pB + (size_t)k0 * FOUT + 4);
    sA[ak+0][ar] = ua0.x; sA[ak+1][ar] = ua0.y;
    sA[ak+2][ar] = ua0.z; sA[ak+3][ar] = ua0.w;
    sA[ak+4][ar] = ua1.x; sA[ak+5][ar] = ua1.y;
    sA[ak+6][ar] = ua1.z; sA[ak+7][ar] = ua1.w;
    sB[bk][bc+0] = ub0.x; sB[bk][bc+1] = ub0.y;
    sB[bk][bc+2] = ub0.z; sB[bk][bc+3] = ub0.w;
    sB[bk][bc+4] = ub1.x; sB[bk][bc+5] = ub1.y;
    sB[bk][bc+6] = ub1.z; sB[bk][bc+7] = ub1.w;
    __syncthreads();
#pragma unroll
    for (int kk = 0; kk < 32; ++kk) {
      float a0 = sA[kk][ty*4+0], a1 = sA[kk][ty*4+1];
      float a2 = sA[kk][ty*4+2], a3 = sA[kk][ty*4+3];
      float b0 = sB[kk][tx*4+0], b1 = sB[kk][tx*4+1];
      float b2 = sB[kk][tx*4+2], b3 = sB[kk][tx*4+3];
      acc[0][0] += a0*b0; acc[0][1] += a0*b1; acc[0][2] += a0*b2; acc[0][3] += a0*b3;
      acc[1][0] += a1*b0; acc[1][1] += a1*b1; acc[1][2] += a1*b2; acc[1][3] += a1*b3;
      acc[2][0] += a2*b0; acc[2][1] += a2*b1; acc[2][2] += a2*b2; acc[2][3] += a2*b3;
      acc[3][0] += a3*b0; acc[3][1] += a3*b1; acc[3][2] += a3*b2; acc[3][3] += a3*b3;
    }
    __syncthreads();
  }

  const int colb = col0 + tx*4;
#pragma unroll
  for (int i = 0; i < 4; ++i) {
    int grow = row0 + ty*4 + i;
    int b = grow >> 11;
    int n = grow & 2047;
    int hh = n >> 8;
    int jj = ((n & 255) << 3) | (colb >> 6);
    int dd = colb & 63;
    float4 v;
    v.x = acc[i][0] > 0.f ? acc[i][0] : SLOPE*acc[i][0];
    v.y = acc[i][1] > 0.f ? acc[i][1] : SLOPE*acc[i][1];
    v.z = acc[i][2] > 0.f ? acc[i][2] : SLOPE*acc[i][2];
    v.w = acc[i][3] > 0.f ? acc[i][3] : SLOPE*acc[i][3];
    *(float4*)(Whr + (((size_t)(b*NHD + hh) * NN) + jj) * DH + dd) = v;
  }
}

// ---------------------------------------------------------------------------
// K2: er[row] = dot(Whr[row][0..63], a)   (row = (b*8+h)*2048 + j), 1 wave/row
// ---------------------------------------------------------------------------
__global__ __launch_bounds__(256) void k_er(
    const float* __restrict__ Whr, const float* __restrict__ av,
    float* __restrict__ er)
{
  int gtid = blockIdx.x * 256 + threadIdx.x;
  int row  = gtid >> 6;
  int lane = threadIdx.x & 63;
  float v = Whr[(size_t)row * DH + lane] * av[lane];
#pragma unroll
  for (int off = 32; off; off >>= 1) v += __shfl_down(v, off, 64);
  if (lane == 0) er[row] = v;
}

// ---------------------------------------------------------------------------
// K3: per (b,h): w[j] = exp(er[j] - max_j er)   (in place), 1 block per (b,h)
// ---------------------------------------------------------------------------
__global__ __launch_bounds__(256) void k_softmax_w(float* __restrict__ er)
{
  __shared__ float wm[4];
  float* p = er + (size_t)blockIdx.x * NN;
  float m = -1e30f;
  for (int j = threadIdx.x; j < NN; j += 256) m = fmaxf(m, p[j]);
#pragma unroll
  for (int off = 32; off; off >>= 1) m = fmaxf(m, __shfl_down(m, off, 64));
  if ((threadIdx.x & 63) == 0) wm[threadIdx.x >> 6] = m;
  __syncthreads();
  float mm = fmaxf(fmaxf(wm[0], wm[1]), fmaxf(wm[2], wm[3]));
  for (int j = threadIdx.x; j < NN; j += 256) p[j] = expf(p[j] - mm);
}

// ---------------------------------------------------------------------------
// K4: Vt[b][c][j] (bf16, j-contiguous for MFMA B-fragments):
//   c<512:       w[b,h,j]*Whr[b,h,j,d]  (h=c>>6, d=c&63)
//   512<=c<520:  w[b,c-512,j]           (denominator columns)
//   else:        0
// ---------------------------------------------------------------------------
__global__ __launch_bounds__(256) void k_build_vt(
    const float* __restrict__ Whr, const float* __restrict__ w,
    unsigned short* __restrict__ Vt)
{
  const int lane = threadIdx.x & 63, wv = threadIdx.x >> 6;
  const int c = blockIdx.y * 4 + wv;     // 0..575
  const int b = blockIdx.z;
  const int j = blockIdx.x * 512 + lane * 8;
  uint4 o = {0u, 0u, 0u, 0u};
  if (c < 512) {
    const int hh = c >> 6, dd = c & 63;
    const size_t r = ((size_t)(b*NHD + hh))*NN + j;
    const float* wp = w + r;
    const float* hp = Whr + r*DH + dd;
    float v[8];
#pragma unroll
    for (int q = 0; q < 8; ++q) v[q] = wp[q] * hp[(size_t)q*DH];
    o.x = bfpair(v[0], v[1]); o.y = bfpair(v[2], v[3]);
    o.z = bfpair(v[4], v[5]); o.w = bfpair(v[6], v[7]);
  } else if (c < 520) {
    const size_t r = ((size_t)(b*NHD + (c - 512)))*NN + j;
    float4 a0 = *(const float4*)(w + r);
    float4 a1 = *(const float4*)(w + r + 4);
    o.x = bfpair(a0.x, a0.y); o.y = bfpair(a0.z, a0.w);
    o.z = bfpair(a1.x, a1.y); o.w = bfpair(a1.z, a1.w);
  }
  *(uint4*)(Vt + ((size_t)(b*VC + c))*NN + j) = o;
}

// ---------------------------------------------------------------------------
// K5: C[8192][576] (f32) = adj(0/1 bf16) @ Vt^T per batch, MFMA 32x32x16 bf16.
//   Block 128(i) x 64(c), BK=64, 4 waves 2x2, wave tile 64x32 (2 acc).
//   A: int32->bf16 inline (regs -> padded LDS, (x|y<<16)*0x3F80 exact).
//   B: global_load_lds width 16, XOR-swizzled global addresses so natural
//      (unpadded) LDS layout reads conflict-free with ds_read_b128.
//   Grid swizzle: blockIdx%8 -> XCD keeps one adj row-stripe group per XCD L2.
// ---------------------------------------------------------------------------
__global__ __launch_bounds__(256) void k_attn_mfma(
    const int* __restrict__ adj, const unsigned short* __restrict__ Vt,
    float* __restrict__ C)
{
  __shared__ unsigned short sA[128][72];   // [i][k], +8 pad: 2-way banks (free)
  __shared__ unsigned short sB[64][64];    // [c][k], unpadded (lds-DMA target)
  const int tid = threadIdx.x;
  const int lane = tid & 63, wv = tid >> 6;
  const int Bid = blockIdx.x;
  const int g8 = Bid & 7, idx = Bid >> 3;
  const int ct = idx >> 3, sg = idx & 7;       // ct: 0..8, sg: 0..7
  const int c0 = ct * 64;
  const int row0 = (g8 * 8 + sg) * 128;        // flat row in [0,8192)
  const int b = row0 >> 11;

  // B-side: per-wave async-load pointers (2 instrs/wave cover 64x64 bf16 tile)
  const unsigned short* pB[2];
  unsigned short* dB[2];
#pragma unroll
  for (int t = 0; t < 2; ++t) {
    int I  = wv + t*4;                 // 0..7: rows [I*8, I*8+8) of sB
    int rl = I*8 + (lane >> 3);        // c-local row this lane feeds
    int gk = (lane & 7) ^ (rl & 7);    // swizzle: LDS slot (rl, lane&7) holds global kgroup gk
    pB[t] = Vt + ((size_t)(b*VC + c0 + rl))*NN + gk*8;
    dB[t] = &sB[0][0] + I*512;         // wave-uniform LDS base (I*1024 bytes)
  }
  // A-side staging: 4 rounds, each thread 8 ints -> 8 bf16 -> 1 ds_write_b128
  const int* adjp = adj + (size_t)b*NN*NN + (size_t)(row0 & 2047)*NN
                    + (tid >> 3)*NN + (tid & 7)*8;
  unsigned short* sAp = &sA[tid >> 3][(tid & 7)*8];

  const int wi = wv >> 1, wc = wv & 1;
  const int l31 = lane & 31, half = lane >> 5;
  f32x16 acc0 = {}; f32x16 acc1 = {};
  const unsigned short* aRd0 = &sA[wi*64 +      l31][half*8];
  const unsigned short* aRd1 = &sA[wi*64 + 32 + l31][half*8];
  const int nloc = wc*32 + l31;

  for (int k0 = 0; k0 < NN; k0 += 64) {
    load_lds16(pB[0] + k0, dB[0]);
    load_lds16(pB[1] + k0, dB[1]);
#pragma unroll
    for (int rr = 0; rr < 4; ++rr) {
      const int* p = adjp + rr*32*NN + k0;
      int4 q0 = *(const int4*)p;
      int4 q1 = *(const int4*)(p + 4);
      uint4 u;
      u.x = (unsigned)(q0.x | (q0.y << 16)) * 0x3F80u;
      u.y = (unsigned)(q0.z | (q0.w << 16)) * 0x3F80u;
      u.z = (unsigned)(q1.x | (q1.y << 16)) * 0x3F80u;
      u.w = (unsigned)(q1.z | (q1.w << 16)) * 0x3F80u;
      *(uint4*)(sAp + rr*32*72) = u;
    }
    __syncthreads();
#pragma unroll
    for (int kb = 0; kb < 4; ++kb) {
      int kg = (kb*2 + half) ^ (lane & 7);
      bhalf8 bf = *(const bhalf8*)&sB[nloc][kg*8];
      bhalf8 a0 = *(const bhalf8*)(aRd0 + kb*16);
      bhalf8 a1 = *(const bhalf8*)(aRd1 + kb*16);
      acc0 = __builtin_amdgcn_mfma_f32_32x32x16_bf16(a0, bf, acc0, 0, 0, 0);
      acc1 = __builtin_amdgcn_mfma_f32_32x32x16_bf16(a1, bf, acc1, 0, 0, 0);
    }
    __syncthreads();
  }
  // C/D layout (32x32): col=lane&31, row=(reg&3)+8*(reg>>2)+4*(lane>>5)
  float* Cp = C + ((size_t)(row0 + wi*64))*VC + c0 + wc*32 + l31;
#pragma unroll
  for (int mi = 0; mi < 2; ++mi) {
    const f32x16 a = mi ? acc1 : acc0;
#pragma unroll
    for (int reg = 0; reg < 16; ++reg) {
      int irow = (reg & 3) + 8*(reg >> 2) + 4*half + mi*32;
      Cp[(size_t)irow * VC] = a[reg];
    }
  }
}

// ---------------------------------------------------------------------------
// K6: out[b][n][f] = elu( C[b][i][h*64+d] / C[b][i][512+h] )
//     n = h*256 + (i>>3), f = (i&7)*64 + d
// ---------------------------------------------------------------------------
__global__ __launch_bounds__(256) void k_epilogue(
    const float* __restrict__ C, float* __restrict__ out)
{
  int idx = blockIdx.x * 256 + threadIdx.x;  // ((b*NN+i)*8+h)*64+d
  int d  = idx & 63;
  int t  = idx >> 6;
  int hh = t & 7;
  int bi = t >> 3;           // b*NN + i
  int i  = bi & 2047, b = bi >> 11;
  float num = C[(size_t)bi * VC + (hh << 6) + d];
  float den = C[(size_t)bi * VC + 512 + hh];
  float v = num / den;
  v = v > 0.f ? v : expm1f(v);
  int n = (hh << 8) | (i >> 3);
  int f = ((i & 7) << 6) | d;
  out[((size_t)b * NN + n) * FOUT + f] = v;
}

// ---------------------------------------------------------------------------
extern "C" void kernel_launch(void* const* d_in, const int* in_sizes, int n_in,
                              void* d_out, int out_size, void* d_ws, size_t ws_size,
                              hipStream_t stream)
{
  const float* hin = (const float*)d_in[0];   // h   f32 [4,2048,512]
  const int*   adj = (const int*)d_in[1];     // adj int32 [4,2048,2048]
  // d_in[2] = W_l : mathematically dead (softmax(el[i]+er[j]) == softmax(er[j]))
  const float* Wr  = (const float*)d_in[3];   // W_r f32 [512,512]
  const float* av  = (const float*)d_in[4];   // a   f32 [64,1]
  float* out = (float*)d_out;

  char* ws = (char*)d_ws;
  const size_t vtBytes = (size_t)NB * VC * NN * 2;     //  9.44 MB
  unsigned short* Vt = (unsigned short*)ws;            // [0, 9.44 MB)
  float* wexp = (float*)(ws + vtBytes);                // 256 KB (er then w)
  float* Whr  = (float*)(ws + vtBytes + 262144);       // 16.78 MB, dead after K4
  float* C    = Whr;                                   // alias: C (18.87 MB) overlays
                                                       // dead Whr; total ws ~28.6 MB
  k_gemm_whr <<<dim3(FOUT/64, NB*NN/64), 256, 0, stream>>>(hin, Wr, Whr);
  k_er       <<<dim3(NB*NHD*NN/4),       256, 0, stream>>>(Whr, av, wexp);
  k_softmax_w<<<dim3(NB*NHD),            256, 0, stream>>>(wexp);
  k_build_vt <<<dim3(NN/512, VC/4, NB),  256, 0, stream>>>(Whr, wexp, Vt);
  k_attn_mfma<<<dim3(9*64),              256, 0, stream>>>(adj, Vt, C);
  k_epilogue <<<dim3(NB*NN*FOUT/256),    256, 0, stream>>>(C, out);
}

// Round 4
// 220.589 us; speedup vs baseline: 2.8545x; 1.2910x over previous
//
#include <hip/hip_runtime.h>

// Problem constants (B,N,F_in,F_out fixed by setup_inputs)
#define NB   4
#define NN   2048
#define FIN  512
#define FOUT 512
#define NHD  8
#define DH   64
#define VC   576   // padded V columns: 512 data (8 heads x 64) + 8 Z cols + 56 zero pad
#define SLOPE 0.2f

typedef __attribute__((ext_vector_type(8)))  short bhalf8;
typedef __attribute__((ext_vector_type(16))) float f32x16;

__device__ __forceinline__ void load_lds16(const void* g, void* l) {
  __builtin_amdgcn_global_load_lds(
      (const __attribute__((address_space(1))) unsigned int*)g,
      (__attribute__((address_space(3))) unsigned int*)l, 16, 0, 0);
}

// RNE float->bf16 pair pack (values finite, no NaN in this pipeline)
__device__ __forceinline__ unsigned int bfpair(float lo, float hi) {
  unsigned int a = __float_as_uint(lo), b = __float_as_uint(hi);
  a = (a + 0x7FFFu + ((a >> 16) & 1u)) >> 16;
  b = (b + 0x7FFFu + ((b >> 16) & 1u)) & 0xFFFF0000u;
  return a | b;
}

// split x,y into bf16 hi (RNE) + bf16 lo (RNE of residual); returns packed pairs
__device__ __forceinline__ void split2(float x, float y,
                                       unsigned int& hp, unsigned int& lp) {
  unsigned int ux = __float_as_uint(x), uy = __float_as_uint(y);
  unsigned int rx = (ux + 0x7FFFu + ((ux >> 16) & 1u)) & 0xFFFF0000u;
  unsigned int ry = (uy + 0x7FFFu + ((uy >> 16) & 1u)) & 0xFFFF0000u;
  float lx = x - __uint_as_float(rx);
  float ly = y - __uint_as_float(ry);
  unsigned int vx = __float_as_uint(lx), vy = __float_as_uint(ly);
  hp = (rx >> 16) | ry;
  lp = ((vx + 0x7FFFu + ((vx >> 16) & 1u)) >> 16)
     | ((vy + 0x7FFFu + ((vy >> 16) & 1u)) & 0xFFFF0000u);
}

// ---------------------------------------------------------------------------
// P1: h (f32 [8192][512]) -> hHi, hLo (bf16 [8192][512], split precision)
// ---------------------------------------------------------------------------
__global__ __launch_bounds__(256) void k_split_h(
    const float* __restrict__ h,
    unsigned short* __restrict__ hHi, unsigned short* __restrict__ hLo)
{
  size_t base = ((size_t)blockIdx.x * 256 + threadIdx.x) * 8;
  float4 a = *(const float4*)(h + base);
  float4 b = *(const float4*)(h + base + 4);
  uint4 uh, ul;
  split2(a.x, a.y, uh.x, ul.x);
  split2(a.z, a.w, uh.y, ul.y);
  split2(b.x, b.y, uh.z, ul.z);
  split2(b.z, b.w, uh.w, ul.w);
  *(uint4*)(hHi + base) = uh;
  *(uint4*)(hLo + base) = ul;
}

// ---------------------------------------------------------------------------
// P2: Wr (f32 [512k][512n]) -> WrT_hi/lo (bf16 [512n][512k]) via LDS transpose
// ---------------------------------------------------------------------------
__global__ __launch_bounds__(256) void k_prep_wr(
    const float* __restrict__ Wr,
    unsigned short* __restrict__ wTh, unsigned short* __restrict__ wTl)
{
  __shared__ float s[64][65];
  const int t = threadIdx.x;
  const int k0 = blockIdx.y * 64, n0 = blockIdx.x * 64;
#pragma unroll
  for (int p = 0; p < 4; ++p) {
    int row = p * 16 + (t >> 4);       // k-local
    int col = (t & 15) * 4;            // n-local
    float4 v = *(const float4*)(Wr + (size_t)(k0 + row) * FOUT + n0 + col);
    s[row][col] = v.x; s[row][col+1] = v.y; s[row][col+2] = v.z; s[row][col+3] = v.w;
  }
  __syncthreads();
  const int n = t >> 2;           // 0..63
  const int ks = (t & 3) * 16;    // 0,16,32,48
  uint4 h0, h1, l0, l1;
  split2(s[ks+ 0][n], s[ks+ 1][n], h0.x, l0.x);
  split2(s[ks+ 2][n], s[ks+ 3][n], h0.y, l0.y);
  split2(s[ks+ 4][n], s[ks+ 5][n], h0.z, l0.z);
  split2(s[ks+ 6][n], s[ks+ 7][n], h0.w, l0.w);
  split2(s[ks+ 8][n], s[ks+ 9][n], h1.x, l1.x);
  split2(s[ks+10][n], s[ks+11][n], h1.y, l1.y);
  split2(s[ks+12][n], s[ks+13][n], h1.z, l1.z);
  split2(s[ks+14][n], s[ks+15][n], h1.w, l1.w);
  size_t o = (size_t)(n0 + n) * FIN + k0 + ks;
  *(uint4*)(wTh + o) = h0; *(uint4*)(wTh + o + 8) = h1;
  *(uint4*)(wTl + o) = l0; *(uint4*)(wTl + o + 8) = l1;
}

// ---------------------------------------------------------------------------
// K1: Whr = leaky_relu(h @ Wr) via split-bf16 MFMA (hi*hi + hi*lo + lo*hi),
//     fp32-grade accuracy. BM=128, BN=64, BK=64; waves 2x2, wave tile 64x32.
//     All operands staged via global_load_lds w16 with XOR-swizzled k-groups.
//     Epilogue applies leaky_relu + raw-reshape remap store (d-contiguous).
// ---------------------------------------------------------------------------
__global__ __launch_bounds__(256) void k_gemm_whr_mfma(
    const unsigned short* __restrict__ hHi, const unsigned short* __restrict__ hLo,
    const unsigned short* __restrict__ wTh, const unsigned short* __restrict__ wTl,
    float* __restrict__ Whr)
{
  __shared__ unsigned short sAh[128*64], sAl[128*64];
  __shared__ unsigned short sBh[64*64],  sBl[64*64];
  const int tid = threadIdx.x, lane = tid & 63, wv = tid >> 6;
  const int Bid = blockIdx.x;
  const int g8 = Bid & 7, idx = Bid >> 3;     // XCD-grouped: 8 row-groups/XCD
  const int sg = idx >> 3, ct = idx & 7;      // col tiles sweep fastest (share A)
  const int c0 = ct * 64;
  const int row0 = (g8 * 8 + sg) * 128;

  // staging pointers (swizzle on global k-group so natural LDS layout is clean)
  const unsigned short* pAh[4]; const unsigned short* pAl[4];
  unsigned short *dAh[4], *dAl[4];
#pragma unroll
  for (int t = 0; t < 4; ++t) {
    int I  = wv + t * 4;                 // 0..15 -> rows [I*8, I*8+8)
    int rl = I * 8 + (lane >> 3);
    int gk = (lane & 7) ^ (rl & 7);
    pAh[t] = hHi + (size_t)(row0 + rl) * FIN + gk * 8;
    pAl[t] = hLo + (size_t)(row0 + rl) * FIN + gk * 8;
    dAh[t] = sAh + I * 512;  dAl[t] = sAl + I * 512;
  }
  const unsigned short* pBh[2]; const unsigned short* pBl[2];
  unsigned short *dBh[2], *dBl[2];
#pragma unroll
  for (int t = 0; t < 2; ++t) {
    int I  = wv + t * 4;                 // 0..7 -> rows [I*8, I*8+8)
    int rl = I * 8 + (lane >> 3);
    int gk = (lane & 7) ^ (rl & 7);
    pBh[t] = wTh + (size_t)(c0 + rl) * FIN + gk * 8;
    pBl[t] = wTl + (size_t)(c0 + rl) * FIN + gk * 8;
    dBh[t] = sBh + I * 512;  dBl[t] = sBl + I * 512;
  }

  const int wi = wv >> 1, wc = wv & 1;
  const int l31 = lane & 31, half = lane >> 5;
  const int aoff0 = (wi*64 +      l31) * 64;
  const int aoff1 = (wi*64 + 32 + l31) * 64;
  const int boff  = (wc*32 +      l31) * 64;
  f32x16 acc0 = {}; f32x16 acc1 = {};

  for (int k0 = 0; k0 < FIN; k0 += 64) {
#pragma unroll
    for (int t = 0; t < 4; ++t) { load_lds16(pAh[t] + k0, dAh[t]);
                                  load_lds16(pAl[t] + k0, dAl[t]); }
#pragma unroll
    for (int t = 0; t < 2; ++t) { load_lds16(pBh[t] + k0, dBh[t]);
                                  load_lds16(pBl[t] + k0, dBl[t]); }
    __syncthreads();
#pragma unroll
    for (int kb = 0; kb < 4; ++kb) {
      int kg = ((kb*2 + half) ^ (lane & 7)) * 8;
      bhalf8 bh  = *(const bhalf8*)&sBh[boff  + kg];
      bhalf8 bl  = *(const bhalf8*)&sBl[boff  + kg];
      bhalf8 a0h = *(const bhalf8*)&sAh[aoff0 + kg];
      bhalf8 a0l = *(const bhalf8*)&sAl[aoff0 + kg];
      bhalf8 a1h = *(const bhalf8*)&sAh[aoff1 + kg];
      bhalf8 a1l = *(const bhalf8*)&sAl[aoff1 + kg];
      acc0 = __builtin_amdgcn_mfma_f32_32x32x16_bf16(a0h, bh, acc0, 0, 0, 0);
      acc1 = __builtin_amdgcn_mfma_f32_32x32x16_bf16(a1h, bh, acc1, 0, 0, 0);
      acc0 = __builtin_amdgcn_mfma_f32_32x32x16_bf16(a0l, bh, acc0, 0, 0, 0);
      acc1 = __builtin_amdgcn_mfma_f32_32x32x16_bf16(a1l, bh, acc1, 0, 0, 0);
      acc0 = __builtin_amdgcn_mfma_f32_32x32x16_bf16(a0h, bl, acc0, 0, 0, 0);
      acc1 = __builtin_amdgcn_mfma_f32_32x32x16_bf16(a1h, bl, acc1, 0, 0, 0);
    }
    __syncthreads();
  }

  // epilogue: leaky_relu + remap. col>>6 == ct (tile 64-aligned, width 64)
  const int colb = c0 + wc*32 + l31;
#pragma unroll
  for (int mi = 0; mi < 2; ++mi) {
    const f32x16 a = mi ? acc1 : acc0;
#pragma unroll
    for (int reg = 0; reg < 16; ++reg) {
      int grow = row0 + wi*64 + mi*32 + ((reg & 3) + 8*(reg >> 2) + 4*half);
      int b  = grow >> 11;
      int n  = grow & 2047;
      int hd = n >> 8;
      int jj = ((n & 255) << 3) | ct;
      int dd = colb & 63;
      float v = a[reg];
      v = v > 0.f ? v : SLOPE * v;
      Whr[(((size_t)(b*NHD + hd)) * NN + jj) * DH + dd] = v;
    }
  }
}

// ---------------------------------------------------------------------------
// K2: er[row] = dot(Whr[row][0..63], a)   (row = (b*8+h)*2048 + j), 1 wave/row
// ---------------------------------------------------------------------------
__global__ __launch_bounds__(256) void k_er(
    const float* __restrict__ Whr, const float* __restrict__ av,
    float* __restrict__ er)
{
  int gtid = blockIdx.x * 256 + threadIdx.x;
  int row  = gtid >> 6;
  int lane = threadIdx.x & 63;
  float v = Whr[(size_t)row * DH + lane] * av[lane];
#pragma unroll
  for (int off = 32; off; off >>= 1) v += __shfl_down(v, off, 64);
  if (lane == 0) er[row] = v;
}

// ---------------------------------------------------------------------------
// K3: per (b,h): w[j] = exp(er[j] - max_j er)   (in place), 1 block per (b,h)
// ---------------------------------------------------------------------------
__global__ __launch_bounds__(256) void k_softmax_w(float* __restrict__ er)
{
  __shared__ float wm[4];
  float* p = er + (size_t)blockIdx.x * NN;
  float m = -1e30f;
  for (int j = threadIdx.x; j < NN; j += 256) m = fmaxf(m, p[j]);
#pragma unroll
  for (int off = 32; off; off >>= 1) m = fmaxf(m, __shfl_down(m, off, 64));
  if ((threadIdx.x & 63) == 0) wm[threadIdx.x >> 6] = m;
  __syncthreads();
  float mm = fmaxf(fmaxf(wm[0], wm[1]), fmaxf(wm[2], wm[3]));
  for (int j = threadIdx.x; j < NN; j += 256) p[j] = expf(p[j] - mm);
}

// ---------------------------------------------------------------------------
// K4: Vt[b][c][j] (bf16, j-contiguous for MFMA B-fragments):
//   c<512:       w[b,h,j]*Whr[b,h,j,d]  (h=c>>6, d=c&63)
//   512<=c<520:  w[b,c-512,j]           (denominator columns)
//   else:        0
// ---------------------------------------------------------------------------
__global__ __launch_bounds__(256) void k_build_vt(
    const float* __restrict__ Whr, const float* __restrict__ w,
    unsigned short* __restrict__ Vt)
{
  const int lane = threadIdx.x & 63, wv = threadIdx.x >> 6;
  const int c = blockIdx.y * 4 + wv;     // 0..575
  const int b = blockIdx.z;
  const int j = blockIdx.x * 512 + lane * 8;
  uint4 o = {0u, 0u, 0u, 0u};
  if (c < 512) {
    const int hh = c >> 6, dd = c & 63;
    const size_t r = ((size_t)(b*NHD + hh))*NN + j;
    const float* wp = w + r;
    const float* hp = Whr + r*DH + dd;
    float v[8];
#pragma unroll
    for (int q = 0; q < 8; ++q) v[q] = wp[q] * hp[(size_t)q*DH];
    o.x = bfpair(v[0], v[1]); o.y = bfpair(v[2], v[3]);
    o.z = bfpair(v[4], v[5]); o.w = bfpair(v[6], v[7]);
  } else if (c < 520) {
    const size_t r = ((size_t)(b*NHD + (c - 512)))*NN + j;
    float4 a0 = *(const float4*)(w + r);
    float4 a1 = *(const float4*)(w + r + 4);
    o.x = bfpair(a0.x, a0.y); o.y = bfpair(a0.z, a0.w);
    o.z = bfpair(a1.x, a1.y); o.w = bfpair(a1.z, a1.w);
  }
  *(uint4*)(Vt + ((size_t)(b*VC + c))*NN + j) = o;
}

// ---------------------------------------------------------------------------
// K5: C[8192][576] (f32) = adj(0/1 bf16) @ Vt^T per batch, MFMA 32x32x16 bf16.
// ---------------------------------------------------------------------------
__global__ __launch_bounds__(256) void k_attn_mfma(
    const int* __restrict__ adj, const unsigned short* __restrict__ Vt,
    float* __restrict__ C)
{
  __shared__ unsigned short sA[128][72];   // [i][k], +8 pad
  __shared__ unsigned short sB[64][64];    // [c][k], unpadded (lds-DMA target)
  const int tid = threadIdx.x;
  const int lane = tid & 63, wv = tid >> 6;
  const int Bid = blockIdx.x;
  const int g8 = Bid & 7, idx = Bid >> 3;
  const int ct = idx >> 3, sg = idx & 7;       // ct: 0..8, sg: 0..7
  const int c0 = ct * 64;
  const int row0 = (g8 * 8 + sg) * 128;        // flat row in [0,8192)
  const int b = row0 >> 11;

  const unsigned short* pB[2];
  unsigned short* dB[2];
#pragma unroll
  for (int t = 0; t < 2; ++t) {
    int I  = wv + t*4;
    int rl = I*8 + (lane >> 3);
    int gk = (lane & 7) ^ (rl & 7);
    pB[t] = Vt + ((size_t)(b*VC + c0 + rl))*NN + gk*8;
    dB[t] = &sB[0][0] + I*512;
  }
  const int* adjp = adj + (size_t)b*NN*NN + (size_t)(row0 & 2047)*NN
                    + (tid >> 3)*NN + (tid & 7)*8;
  unsigned short* sAp = &sA[tid >> 3][(tid & 7)*8];

  const int wi = wv >> 1, wc = wv & 1;
  const int l31 = lane & 31, half = lane >> 5;
  f32x16 acc0 = {}; f32x16 acc1 = {};
  const unsigned short* aRd0 = &sA[wi*64 +      l31][half*8];
  const unsigned short* aRd1 = &sA[wi*64 + 32 + l31][half*8];
  const int nloc = wc*32 + l31;

  for (int k0 = 0; k0 < NN; k0 += 64) {
    load_lds16(pB[0] + k0, dB[0]);
    load_lds16(pB[1] + k0, dB[1]);
#pragma unroll
    for (int rr = 0; rr < 4; ++rr) {
      const int* p = adjp + rr*32*NN + k0;
      int4 q0 = *(const int4*)p;
      int4 q1 = *(const int4*)(p + 4);
      uint4 u;
      u.x = (unsigned)(q0.x | (q0.y << 16)) * 0x3F80u;
      u.y = (unsigned)(q0.z | (q0.w << 16)) * 0x3F80u;
      u.z = (unsigned)(q1.x | (q1.y << 16)) * 0x3F80u;
      u.w = (unsigned)(q1.z | (q1.w << 16)) * 0x3F80u;
      *(uint4*)(sAp + rr*32*72) = u;
    }
    __syncthreads();
#pragma unroll
    for (int kb = 0; kb < 4; ++kb) {
      int kg = (kb*2 + half) ^ (lane & 7);
      bhalf8 bf = *(const bhalf8*)&sB[nloc][kg*8];
      bhalf8 a0 = *(const bhalf8*)(aRd0 + kb*16);
      bhalf8 a1 = *(const bhalf8*)(aRd1 + kb*16);
      acc0 = __builtin_amdgcn_mfma_f32_32x32x16_bf16(a0, bf, acc0, 0, 0, 0);
      acc1 = __builtin_amdgcn_mfma_f32_32x32x16_bf16(a1, bf, acc1, 0, 0, 0);
    }
    __syncthreads();
  }
  float* Cp = C + ((size_t)(row0 + wi*64))*VC + c0 + wc*32 + l31;
#pragma unroll
  for (int mi = 0; mi < 2; ++mi) {
    const f32x16 a = mi ? acc1 : acc0;
#pragma unroll
    for (int reg = 0; reg < 16; ++reg) {
      int irow = (reg & 3) + 8*(reg >> 2) + 4*half + mi*32;
      Cp[(size_t)irow * VC] = a[reg];
    }
  }
}

// ---------------------------------------------------------------------------
// K6: out[b][n][f] = elu( C[b][i][h*64+d] / C[b][i][512+h] )
//     n = h*256 + (i>>3), f = (i&7)*64 + d
// ---------------------------------------------------------------------------
__global__ __launch_bounds__(256) void k_epilogue(
    const float* __restrict__ C, float* __restrict__ out)
{
  int idx = blockIdx.x * 256 + threadIdx.x;  // ((b*NN+i)*8+h)*64+d
  int d  = idx & 63;
  int t  = idx >> 6;
  int hh = t & 7;
  int bi = t >> 3;           // b*NN + i
  int i  = bi & 2047, b = bi >> 11;
  float num = C[(size_t)bi * VC + (hh << 6) + d];
  float den = C[(size_t)bi * VC + 512 + hh];
  float v = num / den;
  v = v > 0.f ? v : expm1f(v);
  int n = (hh << 8) | (i >> 3);
  int f = ((i & 7) << 6) | d;
  out[((size_t)b * NN + n) * FOUT + f] = v;
}

// ---------------------------------------------------------------------------
extern "C" void kernel_launch(void* const* d_in, const int* in_sizes, int n_in,
                              void* d_out, int out_size, void* d_ws, size_t ws_size,
                              hipStream_t stream)
{
  const float* hin = (const float*)d_in[0];   // h   f32 [4,2048,512]
  const int*   adj = (const int*)d_in[1];     // adj int32 [4,2048,2048]
  // d_in[2] = W_l : mathematically dead (softmax(el[i]+er[j]) == softmax(er[j]))
  const float* Wr  = (const float*)d_in[3];   // W_r f32 [512,512]
  const float* av  = (const float*)d_in[4];   // a   f32 [64,1]
  float* out = (float*)d_out;

  // Workspace overlays (peak 36.7 MB):
  //   [0, 8.39M)      hHi        -> dead after gemm; overlaid by Vt
  //   [8.39M, 16.78M) hLo        -> dead after gemm; overlaid by Vt tail
  //   [16.78M,17.30M) WrT_hi     -> dead after gemm
  //   [17.30M,17.83M) WrT_lo     -> dead after gemm
  //   [17.83M,34.60M) Whr (f32)  -> dead after build_vt; overlaid by C
  //   [34.60M,34.86M) wexp       -> dead after build_vt
  //   [0, 9.44M)      Vt (bf16)  (after gemm)
  //   [17.83M,36.70M) C (f32)    (after build_vt)
  char* ws = (char*)d_ws;
  unsigned short* hHi = (unsigned short*)(ws);
  unsigned short* hLo = (unsigned short*)(ws + 8388608);
  unsigned short* wTh = (unsigned short*)(ws + 16777216);
  unsigned short* wTl = (unsigned short*)(ws + 17301504);
  float* Whr  = (float*)(ws + 17825792);
  float* wexp = (float*)(ws + 34603008);
  unsigned short* Vt = (unsigned short*)(ws);
  float* C    = (float*)(ws + 17825792);

  k_split_h      <<<dim3(2048),           256, 0, stream>>>(hin, hHi, hLo);
  k_prep_wr      <<<dim3(8, 8),           256, 0, stream>>>(Wr, wTh, wTl);
  k_gemm_whr_mfma<<<dim3(512),            256, 0, stream>>>(hHi, hLo, wTh, wTl, Whr);
  k_er           <<<dim3(NB*NHD*NN/4),    256, 0, stream>>>(Whr, av, wexp);
  k_softmax_w    <<<dim3(NB*NHD),         256, 0, stream>>>(wexp);
  k_build_vt     <<<dim3(NN/512, VC/4, NB), 256, 0, stream>>>(Whr, wexp, Vt);
  k_attn_mfma    <<<dim3(9*64),           256, 0, stream>>>(adj, Vt, C);
  k_epilogue     <<<dim3(NB*NN*FOUT/256), 256, 0, stream>>>(C, out);
}